// Round 1
// baseline (110.929 us; speedup 1.0000x reference)
//
#include <hip/hip_runtime.h>
#include <hip/hip_bf16.h>

typedef short bf16x8 __attribute__((ext_vector_type(8)));
typedef float f32x4 __attribute__((ext_vector_type(4)));
typedef unsigned short u16;

#define B_    32
#define L_    8192
#define C_    8
#define P_    512
#define PL_   64
#define PC_   4
#define CED_  8
#define SED_  16
#define D_    256
#define INDIM 2576
#define KPAD  2592      // 81 * 32
#define NROWS (B_ * P_) // 16384

__device__ __forceinline__ u16 f2bf(float f) {
    __hip_bfloat16 h = __float2bfloat16(f);
    return *reinterpret_cast<u16*>(&h);
}
__device__ __forceinline__ float bf2f(u16 u) {
    __hip_bfloat16 h = *reinterpret_cast<__hip_bfloat16*>(&u);
    return __bfloat162float(h);
}

// ---------------------------------------------------------------- weights
// W1 (2576,256) f32 -> W1T (256,2592) bf16, zero-padded K rows
__global__ void k_tw1(const float* __restrict__ W1, u16* __restrict__ w1t) {
    int k = blockIdx.x;        // 0..2591
    int n = threadIdx.x;       // 0..255
    float v = (k < INDIM) ? W1[k * D_ + n] : 0.0f;
    w1t[n * KPAD + k] = (k < INDIM) ? f2bf(v) : (u16)0;
}
// W2 (256,256) f32 -> W2T (256,256) bf16
__global__ void k_tw2(const float* __restrict__ W2, u16* __restrict__ w2t) {
    int k = blockIdx.x;        // 0..255
    int n = threadIdx.x;       // 0..255
    w2t[n * D_ + k] = f2bf(W2[k * D_ + n]);
}

// ---------------------------------------------------------------- feature + LN1
__global__ __launch_bounds__(256) void k_build(
    const float* __restrict__ x, const float* __restrict__ fs,
    const float* __restrict__ ce, const float* __restrict__ se,
    const float* __restrict__ g1, const float* __restrict__ bb1,
    const int* __restrict__ sLp, const int* __restrict__ sCp,
    const int* __restrict__ ctm, const int* __restrict__ sysid,
    u16* __restrict__ featb, int r0)
{
    __shared__ float red[4];
    int r = r0 + blockIdx.x;
    int b = r >> 9, p = r & (P_ - 1);
    int t = threadIdx.x;
    int sL = sLp[b * P_ + p];
    int sC = sCp[b * P_ + p];
    int sid = sysid[0];
    float fsinv = 1.0f / fs[b];

    float vals[11];
    float s1 = 0.0f;
#pragma unroll
    for (int it = 0; it < 11; ++it) {
        int k = t + it * 256;
        float v = 0.0f;
        if (k < INDIM) {
            if (k < 256) {
                int i = k >> 2, j = k & 3;
                int l = (sL + i) & (L_ - 1);
                int c = (sC + j) & (C_ - 1);
                v = x[((b << 13) + l) * C_ + c];
            } else if (k < 512) {
                int i = (k - 256) >> 2;
                int l = (sL + i) & (L_ - 1);
                v = (float)l * fsinv;
            } else if (k < 2560) {
                int m = k - 512;
                int j = (m >> 3) & 3, e = m & 7;
                int c = (sC + j) & (C_ - 1);
                int cid = ctm[sid * 20 + c];
                v = ce[cid * CED_ + e];
            } else {
                v = se[sid * SED_ + (k - 2560)];
            }
        }
        vals[it] = v;
        s1 += v;
    }
    // block reduce s1
#pragma unroll
    for (int off = 32; off > 0; off >>= 1) s1 += __shfl_down(s1, off, 64);
    if ((t & 63) == 0) red[t >> 6] = s1;
    __syncthreads();
    float mu = (red[0] + red[1] + red[2] + red[3]) * (1.0f / (float)INDIM);
    __syncthreads();

    float s2 = 0.0f;
#pragma unroll
    for (int it = 0; it < 11; ++it) {
        int k = t + it * 256;
        if (k < INDIM) { float d = vals[it] - mu; s2 += d * d; }
    }
#pragma unroll
    for (int off = 32; off > 0; off >>= 1) s2 += __shfl_down(s2, off, 64);
    if ((t & 63) == 0) red[t >> 6] = s2;
    __syncthreads();
    float var = (red[0] + red[1] + red[2] + red[3]) * (1.0f / (float)INDIM);
    float rstd = rsqrtf(var + 1e-5f);

    long long base = (long long)blockIdx.x * KPAD;
#pragma unroll
    for (int it = 0; it < 11; ++it) {
        int k = t + it * 256;
        if (k < INDIM) {
            float nv = (vals[it] - mu) * rstd * g1[k] + bb1[k];
            featb[base + k] = f2bf(nv);
        }
    }
    if (t < KPAD - INDIM) featb[base + INDIM + t] = 0;  // zero K padding
}

// ---------------------------------------------------------------- GEMM1 + SiLU
// feat (nr x 2592) bf16 @ W1 (2592 x 256) -> H bf16 (abs rows)
__global__ __launch_bounds__(256) void k_gemm1(
    const u16* __restrict__ featb, const u16* __restrict__ w1t,
    const float* __restrict__ b1, u16* __restrict__ H, int r0)
{
    __shared__ __attribute__((aligned(16))) u16 aA[64 * 40];
    __shared__ __attribute__((aligned(16))) u16 bB[64 * 40];
    int t = threadIdx.x;
    int bx = blockIdx.x, by = blockIdx.y;
    int lane = t & 63, w = t >> 6;
    int wr = (w >> 1) * 32, wc = (w & 1) * 32;

    f32x4 acc[2][2] = {};
    int ldrow = t >> 2, ldseg = t & 3;
    const u16* ag = featb + (long long)(bx * 64 + ldrow) * KPAD + ldseg * 8;
    const u16* bg = w1t + (long long)(by * 64 + ldrow) * KPAD + ldseg * 8;
    int lidx = ldrow * 40 + ldseg * 8;
    int l15 = lane & 15;
    int koff = (lane >> 4) * 8;

    for (int kk = 0; kk < KPAD / 32; ++kk) {
        bf16x8 av = *(const bf16x8*)(ag + kk * 32);
        bf16x8 bv = *(const bf16x8*)(bg + kk * 32);
        *(bf16x8*)&aA[lidx] = av;
        *(bf16x8*)&bB[lidx] = bv;
        __syncthreads();
        bf16x8 a0 = *(const bf16x8*)&aA[(wr + l15) * 40 + koff];
        bf16x8 a1 = *(const bf16x8*)&aA[(wr + 16 + l15) * 40 + koff];
        bf16x8 b0 = *(const bf16x8*)&bB[(wc + l15) * 40 + koff];
        bf16x8 b1v = *(const bf16x8*)&bB[(wc + 16 + l15) * 40 + koff];
        acc[0][0] = __builtin_amdgcn_mfma_f32_16x16x32_bf16(a0, b0, acc[0][0], 0, 0, 0);
        acc[0][1] = __builtin_amdgcn_mfma_f32_16x16x32_bf16(a0, b1v, acc[0][1], 0, 0, 0);
        acc[1][0] = __builtin_amdgcn_mfma_f32_16x16x32_bf16(a1, b0, acc[1][0], 0, 0, 0);
        acc[1][1] = __builtin_amdgcn_mfma_f32_16x16x32_bf16(a1, b1v, acc[1][1], 0, 0, 0);
        __syncthreads();
    }

    int colg0 = by * 64 + wc;
#pragma unroll
    for (int fm = 0; fm < 2; ++fm)
#pragma unroll
        for (int fn = 0; fn < 2; ++fn)
#pragma unroll
            for (int j = 0; j < 4; ++j) {
                int row = r0 + bx * 64 + wr + fm * 16 + (lane >> 4) * 4 + j;
                int col = colg0 + fn * 16 + l15;
                float v = acc[fm][fn][j] + b1[col];
                v = v * (1.0f / (1.0f + expf(-v)));   // SiLU
                H[(long long)row * D_ + col] = f2bf(v);
            }
}

// ---------------------------------------------------------------- LN2 + GEMM2
__global__ __launch_bounds__(256) void k_ln2gemm2(
    const u16* __restrict__ H, const u16* __restrict__ w2t,
    const float* __restrict__ g2, const float* __restrict__ bb2,
    const float* __restrict__ b2, float* __restrict__ out)
{
    __shared__ __attribute__((aligned(16))) u16 Ah[64 * 264];
    __shared__ float ps1[256], ps2[256];
    int t = threadIdx.x;
    int r0 = blockIdx.x * 64;
    int row = t >> 2, seg = t & 3;

    const u16* hp = H + (long long)(r0 + row) * D_ + seg * 64;
    float s1 = 0.0f, s2 = 0.0f;
    float fv[64];
#pragma unroll
    for (int i8 = 0; i8 < 8; ++i8) {
        bf16x8 hv = *(const bf16x8*)(hp + i8 * 8);
#pragma unroll
        for (int e = 0; e < 8; ++e) {
            u16 u = (u16)hv[e];
            float f = bf2f(u);
            fv[i8 * 8 + e] = f;
            s1 += f; s2 += f * f;
        }
    }
    ps1[t] = s1; ps2[t] = s2;
    __syncthreads();
    float tot1 = ps1[row * 4 + 0] + ps1[row * 4 + 1] + ps1[row * 4 + 2] + ps1[row * 4 + 3];
    float tot2 = ps2[row * 4 + 0] + ps2[row * 4 + 1] + ps2[row * 4 + 2] + ps2[row * 4 + 3];
    float mu = tot1 * (1.0f / (float)D_);
    float var = tot2 * (1.0f / (float)D_) - mu * mu;
    float rstd = rsqrtf(var + 1e-5f);

#pragma unroll
    for (int i8 = 0; i8 < 8; ++i8) {
        bf16x8 pv;
#pragma unroll
        for (int e = 0; e < 8; ++e) {
            int c = seg * 64 + i8 * 8 + e;
            float nv = (fv[i8 * 8 + e] - mu) * rstd * g2[c] + bb2[c];
            pv[e] = (short)f2bf(nv);
        }
        *(bf16x8*)&Ah[row * 264 + seg * 64 + i8 * 8] = pv;
    }
    __syncthreads();

    int lane = t & 63, w = t >> 6;
    int col0 = w * 64;
    int l15 = lane & 15;
    f32x4 acc[4][4] = {};
#pragma unroll
    for (int kk = 0; kk < 8; ++kk) {
        int koff = kk * 32 + (lane >> 4) * 8;
        bf16x8 a[4];
#pragma unroll
        for (int fm = 0; fm < 4; ++fm)
            a[fm] = *(const bf16x8*)&Ah[(fm * 16 + l15) * 264 + koff];
#pragma unroll
        for (int fn = 0; fn < 4; ++fn) {
            bf16x8 bfr = *(const bf16x8*)(w2t + (col0 + fn * 16 + l15) * D_ + koff);
#pragma unroll
            for (int fm = 0; fm < 4; ++fm)
                acc[fm][fn] = __builtin_amdgcn_mfma_f32_16x16x32_bf16(a[fm], bfr, acc[fm][fn], 0, 0, 0);
        }
    }
#pragma unroll
    for (int fm = 0; fm < 4; ++fm)
#pragma unroll
        for (int fn = 0; fn < 4; ++fn)
#pragma unroll
            for (int j = 0; j < 4; ++j) {
                int rowg = r0 + fm * 16 + (lane >> 4) * 4 + j;
                int col = col0 + fn * 16 + l15;
                out[(long long)rowg * D_ + col] = acc[fm][fn][j] + b2[col];
            }
}

// ---------------------------------------------------------------- launch
extern "C" void kernel_launch(void* const* d_in, const int* in_sizes, int n_in,
                              void* d_out, int out_size, void* d_ws, size_t ws_size,
                              hipStream_t stream) {
    const float* x   = (const float*)d_in[0];
    const float* fs  = (const float*)d_in[1];
    const float* ce  = (const float*)d_in[2];
    const float* se  = (const float*)d_in[3];
    const float* g1  = (const float*)d_in[4];
    const float* bb1 = (const float*)d_in[5];
    const float* W1  = (const float*)d_in[6];
    const float* b1  = (const float*)d_in[7];
    const float* g2  = (const float*)d_in[8];
    const float* bb2 = (const float*)d_in[9];
    const float* W2  = (const float*)d_in[10];
    const float* b2  = (const float*)d_in[11];
    const int* sL    = (const int*)d_in[12];
    const int* sC    = (const int*)d_in[13];
    const int* ctm   = (const int*)d_in[14];
    const int* sysid = (const int*)d_in[15];
    float* out = (float*)d_out;

    char* ws = (char*)d_ws;
    const size_t o_w1t  = 0;
    const size_t o_w2t  = (size_t)D_ * KPAD * 2;            // 1,327,104
    const size_t o_h    = o_w2t + (size_t)D_ * D_ * 2;      // 1,458,176
    const size_t o_feat = o_h + (size_t)NROWS * D_ * 2;     // 9,846,784
    u16* w1t   = (u16*)(ws + o_w1t);
    u16* w2t   = (u16*)(ws + o_w2t);
    u16* Hb    = (u16*)(ws + o_h);
    u16* featb = (u16*)(ws + o_feat);

    // adaptive chunking of the feat buffer on available workspace
    size_t featcap = (ws_size > o_feat) ? (ws_size - o_feat) : 0;
    long long rpc = (long long)(featcap / (KPAD * 2));
    rpc &= ~63LL;
    if (rpc < 64) rpc = 64;
    if (rpc > NROWS) rpc = NROWS;

    k_tw1<<<dim3(KPAD), dim3(256), 0, stream>>>(W1, w1t);
    k_tw2<<<dim3(D_), dim3(256), 0, stream>>>(W2, w2t);

    for (int r0 = 0; r0 < NROWS; r0 += (int)rpc) {
        int nr = NROWS - r0; if (nr > rpc) nr = (int)rpc;
        k_build<<<dim3(nr), dim3(256), 0, stream>>>(
            x, fs, ce, se, g1, bb1, sL, sC, ctm, sysid, featb, r0);
        k_gemm1<<<dim3(nr / 64, 4), dim3(256), 0, stream>>>(
            featb, w1t, b1, Hb, r0);
    }
    k_ln2gemm2<<<dim3(NROWS / 64), dim3(256), 0, stream>>>(
        Hb, w2t, g2, bb2, b2, out);
}